// Round 2
// baseline (979.762 us; speedup 1.0000x reference)
//
#include <hip/hip_runtime.h>
#include <hip/hip_bf16.h>
#include <math.h>

#define NB 1024
#define NN 204800
#define NE 1000000

__device__ __forceinline__ float gelu_f(float x) {
    return 0.5f * x * (1.0f + erff(x * 0.70710678118654752f));
}

// ---------------------------------------------------------------------------
// Kernel A: per-graph work. 1024 blocks x 128 threads.
//  - z_proj = LN(GELU(z @ lp_w + lp_b))            -> ws
//  - P1b    = z_proj @ ed_w1[0:128]   + ed_b1      -> ws (bias folded)
//  - P2     = z_proj @ ed_w1[128:256]              -> ws
//  - pe, ps heads                                   -> d_out
// ---------------------------------------------------------------------------
__global__ __launch_bounds__(128) void graph_kernel(
    const float* __restrict__ z,
    const float* __restrict__ lp_w, const float* __restrict__ lp_b,
    const float* __restrict__ lp_g, const float* __restrict__ lp_be,
    const float* __restrict__ ed_w1, const float* __restrict__ ed_b1,
    const float* __restrict__ en_w1, const float* __restrict__ en_b1,
    const float* __restrict__ en_g,  const float* __restrict__ en_be,
    const float* __restrict__ en_w2, const float* __restrict__ en_b2,
    const float* __restrict__ st_w1, const float* __restrict__ st_b1,
    const float* __restrict__ st_g,  const float* __restrict__ st_be,
    const float* __restrict__ st_w2, const float* __restrict__ st_b2,
    float* __restrict__ z_proj, float* __restrict__ p1b, float* __restrict__ p2,
    float* __restrict__ out_pe, float* __restrict__ out_ps)
{
    const int b = blockIdx.x;
    const int t = threadIdx.x;
    __shared__ float zrow[32];
    __shared__ float zp[128];
    __shared__ float red[2];
    __shared__ float eh[64];
    __shared__ float sh[64];

    if (t < 32) zrow[t] = z[b * 32 + t];
    __syncthreads();

    // latent_proj: Linear(32,128) -> GELU -> LN(128)
    float acc = lp_b[t];
    #pragma unroll
    for (int k = 0; k < 32; ++k) acc += zrow[k] * lp_w[k * 128 + t];
    acc = gelu_f(acc);

    // LN over 128 elements held by 128 threads (2 waves)
    float s = acc;
    #pragma unroll
    for (int o = 32; o >= 1; o >>= 1) s += __shfl_xor(s, o, 64);
    if ((t & 63) == 0) red[t >> 6] = s;
    __syncthreads();
    float mu = (red[0] + red[1]) * (1.0f / 128.0f);
    __syncthreads();
    float d = acc - mu;
    s = d * d;
    #pragma unroll
    for (int o = 32; o >= 1; o >>= 1) s += __shfl_xor(s, o, 64);
    if ((t & 63) == 0) red[t >> 6] = s;
    __syncthreads();
    float var = (red[0] + red[1]) * (1.0f / 128.0f);
    float v = d * rsqrtf(var + 1e-5f) * lp_g[t] + lp_be[t];
    zp[t] = v;
    z_proj[b * 128 + t] = v;
    __syncthreads();

    // P1b / P2 rows (edge layer-1 algebraic precompute)
    float a1 = ed_b1[t], a2 = 0.0f;
    #pragma unroll 4
    for (int k = 0; k < 128; ++k) {
        float zv = zp[k];
        a1 += zv * ed_w1[k * 128 + t];
        a2 += zv * ed_w1[(k + 128) * 128 + t];
    }
    p1b[b * 128 + t] = a1;
    p2[b * 128 + t]  = a2;

    // heads: wave0 -> energy, wave1 -> stress
    {
        const int lane = t & 63;
        const bool en = (t < 64);
        const float* w1 = en ? en_w1 : st_w1;
        const float* b1 = en ? en_b1 : st_b1;
        const float* g  = en ? en_g  : st_g;
        const float* be = en ? en_be : st_be;
        float h = b1[lane];
        #pragma unroll
        for (int k = 0; k < 32; ++k) h += zrow[k] * w1[k * 64 + lane];
        h = gelu_f(h);
        float m = h;
        #pragma unroll
        for (int o = 32; o >= 1; o >>= 1) m += __shfl_xor(m, o, 64);
        m *= (1.0f / 64.0f);
        float dd = h - m;
        float vv = dd * dd;
        #pragma unroll
        for (int o = 32; o >= 1; o >>= 1) vv += __shfl_xor(vv, o, 64);
        vv *= (1.0f / 64.0f);
        float hn = dd * rsqrtf(vv + 1e-5f) * g[lane] + be[lane];
        if (en) eh[lane] = hn; else sh[lane] = hn;
    }
    __syncthreads();
    if (t < 2) {
        float a = en_b2[t];
        for (int j = 0; j < 64; ++j) a += eh[j] * en_w2[j * 2 + t];
        out_pe[b * 2 + t] = a;
    }
    if (t >= 64 && t < 73) {
        const int c = t - 64;
        float a = st_b2[c];
        for (int j = 0; j < 64; ++j) a += sh[j] * st_w2[j * 9 + c];
        out_ps[b * 9 + c] = a;
    }
}

// ---------------------------------------------------------------------------
// Kernel B: fused node path. 1600 blocks x 256 threads, 128 nodes/block.
// Thread (tr = t>>4, tc = t&15); thread owns nodes {tr + 16*i}, i=0..7.
// Row ownership stays within one wave -> single __syncthreads after staging.
// ---------------------------------------------------------------------------
__global__ __launch_bounds__(256) void node_kernel(
    const float* __restrict__ node_emb, const int* __restrict__ n2g,
    const float* __restrict__ z_proj,
    const float* __restrict__ ne_w, const float* __restrict__ ne_b,
    const float* __restrict__ ne_g, const float* __restrict__ ne_be,
    const float* __restrict__ nd_w1, const float* __restrict__ nd_b1,
    const float* __restrict__ nd_g, const float* __restrict__ nd_be,
    const float* __restrict__ nd_w2, const float* __restrict__ nd_b2,
    float* __restrict__ out_node)
{
    __shared__ float tile[128][132];
    __shared__ int gidx[128];
    const int t = threadIdx.x;
    const int node0 = blockIdx.x * 128;

    if (t < 128) gidx[t] = n2g[node0 + t];
    // stage node_emb tile [128][128] -> LDS
    {
        const int r0 = t >> 5;
        const int c4 = (t & 31) * 4;
        #pragma unroll
        for (int m = 0; m < 16; ++m) {
            const int rr = r0 + m * 8;
            float4 v = *(const float4*)(node_emb + (size_t)(node0 + rr) * 128 + c4);
            *(float4*)&tile[rr][c4] = v;
        }
    }
    __syncthreads();

    const int tr = t >> 4;
    const int tc = t & 15;

    // ---- layer 1: [128,128]@[128,128], 8 nodes x 8 outs per thread ----
    float acc[8][8];
    #pragma unroll
    for (int i = 0; i < 8; ++i)
        #pragma unroll
        for (int j = 0; j < 8; ++j) acc[i][j] = 0.0f;

    for (int k4 = 0; k4 < 128; k4 += 4) {
        float w[4][8];
        #pragma unroll
        for (int kk = 0; kk < 4; ++kk) {
            float4 wa = *(const float4*)(ne_w + (size_t)(k4 + kk) * 128 + tc * 8);
            float4 wb = *(const float4*)(ne_w + (size_t)(k4 + kk) * 128 + tc * 8 + 4);
            w[kk][0] = wa.x; w[kk][1] = wa.y; w[kk][2] = wa.z; w[kk][3] = wa.w;
            w[kk][4] = wb.x; w[kk][5] = wb.y; w[kk][6] = wb.z; w[kk][7] = wb.w;
        }
        #pragma unroll
        for (int i = 0; i < 8; ++i) {
            float4 iv = *(const float4*)&tile[tr + 16 * i][k4];
            float in4[4] = {iv.x, iv.y, iv.z, iv.w};
            #pragma unroll
            for (int kk = 0; kk < 4; ++kk)
                #pragma unroll
                for (int j = 0; j < 8; ++j)
                    acc[i][j] += in4[kk] * w[kk][j];
        }
    }

    // bias + GELU + LN(128) + add z_proj[gidx]; write node_input back to tile
    {
        float4 b0 = *(const float4*)(ne_b + tc * 8);
        float4 b1 = *(const float4*)(ne_b + tc * 8 + 4);
        float4 g0 = *(const float4*)(ne_g + tc * 8);
        float4 g1 = *(const float4*)(ne_g + tc * 8 + 4);
        float4 e0 = *(const float4*)(ne_be + tc * 8);
        float4 e1 = *(const float4*)(ne_be + tc * 8 + 4);
        float nb[8] = {b0.x,b0.y,b0.z,b0.w,b1.x,b1.y,b1.z,b1.w};
        float ng[8] = {g0.x,g0.y,g0.z,g0.w,g1.x,g1.y,g1.z,g1.w};
        float nbe[8]= {e0.x,e0.y,e0.z,e0.w,e1.x,e1.y,e1.z,e1.w};
        #pragma unroll
        for (int i = 0; i < 8; ++i) {
            const int node = tr + 16 * i;
            float x[8];
            float ssum = 0.0f;
            #pragma unroll
            for (int j = 0; j < 8; ++j) { x[j] = gelu_f(acc[i][j] + nb[j]); ssum += x[j]; }
            #pragma unroll
            for (int o = 1; o < 16; o <<= 1) ssum += __shfl_xor(ssum, o, 64);
            const float mu = ssum * (1.0f / 128.0f);
            float sq = 0.0f;
            #pragma unroll
            for (int j = 0; j < 8; ++j) { x[j] -= mu; sq += x[j] * x[j]; }
            #pragma unroll
            for (int o = 1; o < 16; o <<= 1) sq += __shfl_xor(sq, o, 64);
            const float rstd = rsqrtf(sq * (1.0f / 128.0f) + 1e-5f);
            const int g = gidx[node];
            float4 z0 = *(const float4*)(z_proj + (size_t)g * 128 + tc * 8);
            float4 z1 = *(const float4*)(z_proj + (size_t)g * 128 + tc * 8 + 4);
            float zv[8] = {z0.x,z0.y,z0.z,z0.w,z1.x,z1.y,z1.z,z1.w};
            float4 o0, o1;
            o0.x = x[0]*rstd*ng[0]+nbe[0]+zv[0];
            o0.y = x[1]*rstd*ng[1]+nbe[1]+zv[1];
            o0.z = x[2]*rstd*ng[2]+nbe[2]+zv[2];
            o0.w = x[3]*rstd*ng[3]+nbe[3]+zv[3];
            o1.x = x[4]*rstd*ng[4]+nbe[4]+zv[4];
            o1.y = x[5]*rstd*ng[5]+nbe[5]+zv[5];
            o1.z = x[6]*rstd*ng[6]+nbe[6]+zv[6];
            o1.w = x[7]*rstd*ng[7]+nbe[7]+zv[7];
            *(float4*)&tile[node][tc * 8]     = o0;
            *(float4*)&tile[node][tc * 8 + 4] = o1;
        }
    }
    // rows are wave-private; no block sync needed between layers

    // ---- layer 2: [128,128]@[128,64], 8 nodes x 4 outs per thread ----
    float acc2[8][4];
    #pragma unroll
    for (int i = 0; i < 8; ++i)
        #pragma unroll
        for (int j = 0; j < 4; ++j) acc2[i][j] = 0.0f;

    for (int k4 = 0; k4 < 128; k4 += 4) {
        float w2[4][4];
        #pragma unroll
        for (int kk = 0; kk < 4; ++kk) {
            float4 wv = *(const float4*)(nd_w1 + (size_t)(k4 + kk) * 64 + tc * 4);
            w2[kk][0] = wv.x; w2[kk][1] = wv.y; w2[kk][2] = wv.z; w2[kk][3] = wv.w;
        }
        #pragma unroll
        for (int i = 0; i < 8; ++i) {
            float4 iv = *(const float4*)&tile[tr + 16 * i][k4];
            float in4[4] = {iv.x, iv.y, iv.z, iv.w};
            #pragma unroll
            for (int kk = 0; kk < 4; ++kk)
                #pragma unroll
                for (int j = 0; j < 4; ++j)
                    acc2[i][j] += in4[kk] * w2[kk][j];
        }
    }

    // bias + GELU + LN(64), then layer 3 [64,4] with shuffle reduce
    {
        float4 bb = *(const float4*)(nd_b1 + tc * 4);
        float4 gg = *(const float4*)(nd_g  + tc * 4);
        float4 ee = *(const float4*)(nd_be + tc * 4);
        float b1v[4] = {bb.x,bb.y,bb.z,bb.w};
        float g1v[4] = {gg.x,gg.y,gg.z,gg.w};
        float e1v[4] = {ee.x,ee.y,ee.z,ee.w};
        float w3[4][4];
        #pragma unroll
        for (int j = 0; j < 4; ++j) {
            float4 wv = *(const float4*)(nd_w2 + (size_t)(tc * 4 + j) * 4);
            w3[j][0] = wv.x; w3[j][1] = wv.y; w3[j][2] = wv.z; w3[j][3] = wv.w;
        }
        #pragma unroll
        for (int i = 0; i < 8; ++i) {
            const int node = tr + 16 * i;
            float x[4];
            float ssum = 0.0f;
            #pragma unroll
            for (int j = 0; j < 4; ++j) { x[j] = gelu_f(acc2[i][j] + b1v[j]); ssum += x[j]; }
            #pragma unroll
            for (int o = 1; o < 16; o <<= 1) ssum += __shfl_xor(ssum, o, 64);
            const float mu = ssum * (1.0f / 64.0f);
            float sq = 0.0f;
            #pragma unroll
            for (int j = 0; j < 4; ++j) { x[j] -= mu; sq += x[j] * x[j]; }
            #pragma unroll
            for (int o = 1; o < 16; o <<= 1) sq += __shfl_xor(sq, o, 64);
            const float rstd = rsqrtf(sq * (1.0f / 64.0f) + 1e-5f);
            float p[4] = {0.0f, 0.0f, 0.0f, 0.0f};
            #pragma unroll
            for (int j = 0; j < 4; ++j) {
                const float h = x[j] * rstd * g1v[j] + e1v[j];
                #pragma unroll
                for (int c = 0; c < 4; ++c) p[c] += h * w3[j][c];
            }
            #pragma unroll
            for (int c = 0; c < 4; ++c)
                #pragma unroll
                for (int o = 1; o < 16; o <<= 1) p[c] += __shfl_xor(p[c], o, 64);
            float r = p[0];
            if (tc == 1) r = p[1];
            else if (tc == 2) r = p[2];
            else if (tc == 3) r = p[3];
            if (tc < 4) out_node[(size_t)(node0 + node) * 4 + tc] = r + nd_b2[tc];
        }
    }
}

// ---------------------------------------------------------------------------
// Kernel C: fused edge path. ceil(E/128) blocks x 256 threads, 128 edges/blk.
// layer1 via gathered P1b/P2 tables (algebraic precompute), then fused
// GELU/LN/Linear chain identical in structure to the node kernel.
// ---------------------------------------------------------------------------
__global__ __launch_bounds__(256) void edge_kernel(
    const int* __restrict__ src, const int* __restrict__ dst,
    const int* __restrict__ n2g,
    const float* __restrict__ p1b, const float* __restrict__ p2,
    const float* __restrict__ ed_g1, const float* __restrict__ ed_be1,
    const float* __restrict__ ed_w2, const float* __restrict__ ed_b2,
    const float* __restrict__ ed_g2, const float* __restrict__ ed_be2,
    const float* __restrict__ ed_w3, const float* __restrict__ ed_b3,
    float* __restrict__ out_edge)
{
    __shared__ float tile[128][132];
    __shared__ int gsrc[128];
    __shared__ int gdst[128];
    const int t = threadIdx.x;
    const int e0 = blockIdx.x * 128;

    if (t < 128) {
        const int e = e0 + t;
        const int si = (e < NE) ? src[e] : 0;
        const int di = (e < NE) ? dst[e] : 0;
        gsrc[t] = n2g[si];
        gdst[t] = n2g[di];
    }
    __syncthreads();

    // stage y = GELU(P1b[gs] + P2[gd])
    {
        const int r0 = t >> 5;
        const int c4 = (t & 31) * 4;
        #pragma unroll
        for (int m = 0; m < 16; ++m) {
            const int rr = r0 + m * 8;
            const float4 a = *(const float4*)(p1b + (size_t)gsrc[rr] * 128 + c4);
            const float4 b = *(const float4*)(p2  + (size_t)gdst[rr] * 128 + c4);
            float4 y;
            y.x = gelu_f(a.x + b.x);
            y.y = gelu_f(a.y + b.y);
            y.z = gelu_f(a.z + b.z);
            y.w = gelu_f(a.w + b.w);
            *(float4*)&tile[rr][c4] = y;
        }
    }
    __syncthreads();

    const int tr = t >> 4;
    const int tc = t & 15;

    // LN(128) in place (rows wave-private from here on)
    {
        float4 g0 = *(const float4*)(ed_g1 + tc * 8);
        float4 g1 = *(const float4*)(ed_g1 + tc * 8 + 4);
        float4 e0v = *(const float4*)(ed_be1 + tc * 8);
        float4 e1v = *(const float4*)(ed_be1 + tc * 8 + 4);
        float gv[8] = {g0.x,g0.y,g0.z,g0.w,g1.x,g1.y,g1.z,g1.w};
        float ev[8] = {e0v.x,e0v.y,e0v.z,e0v.w,e1v.x,e1v.y,e1v.z,e1v.w};
        #pragma unroll
        for (int i = 0; i < 8; ++i) {
            const int r = tr + 16 * i;
            float4 x0 = *(const float4*)&tile[r][tc * 8];
            float4 x1 = *(const float4*)&tile[r][tc * 8 + 4];
            float x[8] = {x0.x,x0.y,x0.z,x0.w,x1.x,x1.y,x1.z,x1.w};
            float ssum = 0.0f;
            #pragma unroll
            for (int j = 0; j < 8; ++j) ssum += x[j];
            #pragma unroll
            for (int o = 1; o < 16; o <<= 1) ssum += __shfl_xor(ssum, o, 64);
            const float mu = ssum * (1.0f / 128.0f);
            float sq = 0.0f;
            #pragma unroll
            for (int j = 0; j < 8; ++j) { x[j] -= mu; sq += x[j] * x[j]; }
            #pragma unroll
            for (int o = 1; o < 16; o <<= 1) sq += __shfl_xor(sq, o, 64);
            const float rstd = rsqrtf(sq * (1.0f / 128.0f) + 1e-5f);
            float4 o0, o1;
            o0.x = x[0]*rstd*gv[0]+ev[0]; o0.y = x[1]*rstd*gv[1]+ev[1];
            o0.z = x[2]*rstd*gv[2]+ev[2]; o0.w = x[3]*rstd*gv[3]+ev[3];
            o1.x = x[4]*rstd*gv[4]+ev[4]; o1.y = x[5]*rstd*gv[5]+ev[5];
            o1.z = x[6]*rstd*gv[6]+ev[6]; o1.w = x[7]*rstd*gv[7]+ev[7];
            *(float4*)&tile[r][tc * 8]     = o0;
            *(float4*)&tile[r][tc * 8 + 4] = o1;
        }
    }

    // ---- layer 2: [128,128]@[128,64] ----
    float acc2[8][4];
    #pragma unroll
    for (int i = 0; i < 8; ++i)
        #pragma unroll
        for (int j = 0; j < 4; ++j) acc2[i][j] = 0.0f;

    for (int k4 = 0; k4 < 128; k4 += 4) {
        float w2[4][4];
        #pragma unroll
        for (int kk = 0; kk < 4; ++kk) {
            float4 wv = *(const float4*)(ed_w2 + (size_t)(k4 + kk) * 64 + tc * 4);
            w2[kk][0] = wv.x; w2[kk][1] = wv.y; w2[kk][2] = wv.z; w2[kk][3] = wv.w;
        }
        #pragma unroll
        for (int i = 0; i < 8; ++i) {
            float4 iv = *(const float4*)&tile[tr + 16 * i][k4];
            float in4[4] = {iv.x, iv.y, iv.z, iv.w};
            #pragma unroll
            for (int kk = 0; kk < 4; ++kk)
                #pragma unroll
                for (int j = 0; j < 4; ++j)
                    acc2[i][j] += in4[kk] * w2[kk][j];
        }
    }

    // bias + GELU + LN(64) + layer 3 [64,3]
    {
        float4 bb = *(const float4*)(ed_b2 + tc * 4);
        float4 gg = *(const float4*)(ed_g2 + tc * 4);
        float4 ee = *(const float4*)(ed_be2 + tc * 4);
        float b2v[4] = {bb.x,bb.y,bb.z,bb.w};
        float g2v[4] = {gg.x,gg.y,gg.z,gg.w};
        float e2v[4] = {ee.x,ee.y,ee.z,ee.w};
        float w3[4][3];
        #pragma unroll
        for (int j = 0; j < 4; ++j) {
            const float* wp = ed_w3 + (size_t)(tc * 4 + j) * 3;
            w3[j][0] = wp[0]; w3[j][1] = wp[1]; w3[j][2] = wp[2];
        }
        #pragma unroll
        for (int i = 0; i < 8; ++i) {
            const int e = e0 + tr + 16 * i;
            float x[4];
            float ssum = 0.0f;
            #pragma unroll
            for (int j = 0; j < 4; ++j) { x[j] = gelu_f(acc2[i][j] + b2v[j]); ssum += x[j]; }
            #pragma unroll
            for (int o = 1; o < 16; o <<= 1) ssum += __shfl_xor(ssum, o, 64);
            const float mu = ssum * (1.0f / 64.0f);
            float sq = 0.0f;
            #pragma unroll
            for (int j = 0; j < 4; ++j) { x[j] -= mu; sq += x[j] * x[j]; }
            #pragma unroll
            for (int o = 1; o < 16; o <<= 1) sq += __shfl_xor(sq, o, 64);
            const float rstd = rsqrtf(sq * (1.0f / 64.0f) + 1e-5f);
            float p[3] = {0.0f, 0.0f, 0.0f};
            #pragma unroll
            for (int j = 0; j < 4; ++j) {
                const float h = x[j] * rstd * g2v[j] + e2v[j];
                #pragma unroll
                for (int c = 0; c < 3; ++c) p[c] += h * w3[j][c];
            }
            #pragma unroll
            for (int c = 0; c < 3; ++c)
                #pragma unroll
                for (int o = 1; o < 16; o <<= 1) p[c] += __shfl_xor(p[c], o, 64);
            float r = p[0];
            if (tc == 1) r = p[1];
            else if (tc == 2) r = p[2];
            if (e < NE && tc < 3) out_edge[(size_t)e * 3 + tc] = r + ed_b3[tc];
        }
    }
}

extern "C" void kernel_launch(void* const* d_in, const int* in_sizes, int n_in,
                              void* d_out, int out_size, void* d_ws, size_t ws_size,
                              hipStream_t stream) {
    const float* z        = (const float*)d_in[0];
    const float* node_emb = (const float*)d_in[1];
    const int*   n2g      = (const int*)d_in[2];
    const int*   src      = (const int*)d_in[3];
    const int*   dst      = (const int*)d_in[4];
    const float* lp_w  = (const float*)d_in[5];
    const float* lp_b  = (const float*)d_in[6];
    const float* lp_g  = (const float*)d_in[7];
    const float* lp_be = (const float*)d_in[8];
    const float* ne_w  = (const float*)d_in[9];
    const float* ne_b  = (const float*)d_in[10];
    const float* ne_g  = (const float*)d_in[11];
    const float* ne_be = (const float*)d_in[12];
    const float* nd_w1 = (const float*)d_in[13];
    const float* nd_b1 = (const float*)d_in[14];
    const float* nd_g  = (const float*)d_in[15];
    const float* nd_be = (const float*)d_in[16];
    const float* nd_w2 = (const float*)d_in[17];
    const float* nd_b2 = (const float*)d_in[18];
    const float* ed_w1 = (const float*)d_in[19];
    const float* ed_b1 = (const float*)d_in[20];
    const float* ed_g1 = (const float*)d_in[21];
    const float* ed_be1= (const float*)d_in[22];
    const float* ed_w2 = (const float*)d_in[23];
    const float* ed_b2 = (const float*)d_in[24];
    const float* ed_g2 = (const float*)d_in[25];
    const float* ed_be2= (const float*)d_in[26];
    const float* ed_w3 = (const float*)d_in[27];
    const float* ed_b3 = (const float*)d_in[28];
    const float* en_w1 = (const float*)d_in[29];
    const float* en_b1 = (const float*)d_in[30];
    const float* en_g  = (const float*)d_in[31];
    const float* en_be = (const float*)d_in[32];
    const float* en_w2 = (const float*)d_in[33];
    const float* en_b2 = (const float*)d_in[34];
    const float* st_w1 = (const float*)d_in[35];
    const float* st_b1 = (const float*)d_in[36];
    const float* st_g  = (const float*)d_in[37];
    const float* st_be = (const float*)d_in[38];
    const float* st_w2 = (const float*)d_in[39];
    const float* st_b2 = (const float*)d_in[40];

    float* out       = (float*)d_out;
    float* out_node  = out;                                   // N*4
    float* out_edge  = out + (size_t)NN * 4;                  // E*3
    float* out_pe    = out + (size_t)NN * 4 + (size_t)NE * 3; // B*2
    float* out_ps    = out_pe + (size_t)NB * 2;               // B*9

    float* ws     = (float*)d_ws;
    float* z_proj = ws;            // 1024*128
    float* p1b    = ws + 131072;   // 1024*128
    float* p2     = ws + 262144;   // 1024*128

    graph_kernel<<<NB, 128, 0, stream>>>(
        z, lp_w, lp_b, lp_g, lp_be, ed_w1, ed_b1,
        en_w1, en_b1, en_g, en_be, en_w2, en_b2,
        st_w1, st_b1, st_g, st_be, st_w2, st_b2,
        z_proj, p1b, p2, out_pe, out_ps);

    node_kernel<<<NN / 128, 256, 0, stream>>>(
        node_emb, n2g, z_proj,
        ne_w, ne_b, ne_g, ne_be,
        nd_w1, nd_b1, nd_g, nd_be, nd_w2, nd_b2,
        out_node);

    edge_kernel<<<(NE + 127) / 128, 256, 0, stream>>>(
        src, dst, n2g, p1b, p2,
        ed_g1, ed_be1, ed_w2, ed_b2, ed_g2, ed_be2, ed_w3, ed_b3,
        out_edge);
}

// Round 4
// 779.430 us; speedup vs baseline: 1.2570x; 1.2570x over previous
//
#include <hip/hip_runtime.h>
#include <hip/hip_bf16.h>
#include <math.h>

#define NB 1024
#define NN 204800
#define NE 1000000

// Branch-free GELU(x) = x * Phi(x); erf via Abramowitz-Stegun 7.1.26 (|err|<=1.5e-7)
__device__ __forceinline__ float gelu_f(float x) {
    const float a = fabsf(x) * 0.70710678118654752f;
    const float t = __builtin_amdgcn_rcpf(1.0f + 0.3275911f * a);
    const float poly = t * (0.254829592f + t * (-0.284496736f +
                       t * (1.421413741f + t * (-1.453152027f + t * 1.061405429f))));
    const float e = __expf(-a * a);
    const float erf_a = 1.0f - poly * e;          // erf(|x|/sqrt2) in [0,1)
    return x * (0.5f + 0.5f * copysignf(erf_a, x));
}

// ---------------------------------------------------------------------------
// ws layout (floats, offsets)
// ---------------------------------------------------------------------------
#define WS_P1B   131072    // 1024*128
#define WS_P2    262144    // 1024*128
#define WS_ZW    393216    // 1024*64
#define WS_WG2E  458752    // 128*64   (ed_g1 * ed_w2)
#define WS_WG1N  466944    // 128*64   (ne_g * nd_w1)
#define WS_SE    475136    // 64       colsum(WG2E)
#define WS_C1E   475200    // 64       ed_be1@ed_w2 + ed_b2
#define WS_SN    475264    // 64       colsum(WG1N)
#define WS_CN1   475328    // 64       ne_be@nd_w1 + nd_b1
#define WS_W3GE  475392    // 64*3     (ed_g2 * ed_w3)
#define WS_S3E   475584    // 3
#define WS_C3E   475648    // 3        ed_be2@ed_w3 + ed_b3
#define WS_WN3G  475712    // 64*4     (nd_g * nd_w2)
#define WS_SN3   475968    // 4
#define WS_CN3   476032    // 4        nd_be@nd_w2 + nd_b2

// ---------------------------------------------------------------------------
// Prep kernel: build LN-folded weight tables. 1 block x 256 threads, trivial.
// ---------------------------------------------------------------------------
__global__ __launch_bounds__(256) void prep_kernel(
    const float* __restrict__ ed_g1, const float* __restrict__ ed_be1,
    const float* __restrict__ ed_w2, const float* __restrict__ ed_b2,
    const float* __restrict__ ed_g2, const float* __restrict__ ed_be2,
    const float* __restrict__ ed_w3, const float* __restrict__ ed_b3,
    const float* __restrict__ ne_g,  const float* __restrict__ ne_be,
    const float* __restrict__ nd_w1, const float* __restrict__ nd_b1,
    const float* __restrict__ nd_g,  const float* __restrict__ nd_be,
    const float* __restrict__ nd_w2, const float* __restrict__ nd_b2,
    float* __restrict__ ws)
{
    const int t = threadIdx.x;
    if (t < 64) {                       // edge W2 fold, column j
        const int j = t;
        float s = 0.0f, c = 0.0f;
        for (int k = 0; k < 128; ++k) {
            const float w = ed_w2[k * 64 + j];
            const float wg = ed_g1[k] * w;
            ws[WS_WG2E + k * 64 + j] = wg;
            s += wg; c += ed_be1[k] * w;
        }
        ws[WS_SE + j] = s;
        ws[WS_C1E + j] = c + ed_b2[j];
    } else if (t < 128) {               // node W1 fold, column j
        const int j = t - 64;
        float s = 0.0f, c = 0.0f;
        for (int k = 0; k < 128; ++k) {
            const float w = nd_w1[k * 64 + j];
            const float wg = ne_g[k] * w;
            ws[WS_WG1N + k * 64 + j] = wg;
            s += wg; c += ne_be[k] * w;
        }
        ws[WS_SN + j] = s;
        ws[WS_CN1 + j] = c + nd_b1[j];
    } else if (t < 131) {               // edge W3 fold, column c
        const int j = t - 128;
        float s = 0.0f, c = 0.0f;
        for (int k = 0; k < 64; ++k) {
            const float w = ed_w3[k * 3 + j];
            const float wg = ed_g2[k] * w;
            ws[WS_W3GE + k * 3 + j] = wg;
            s += wg; c += ed_be2[k] * w;
        }
        ws[WS_S3E + j] = s;
        ws[WS_C3E + j] = c + ed_b3[j];
    } else if (t < 135) {               // node W3 fold, column c
        const int j = t - 131;
        float s = 0.0f, c = 0.0f;
        for (int k = 0; k < 64; ++k) {
            const float w = nd_w2[k * 4 + j];
            const float wg = nd_g[k] * w;
            ws[WS_WN3G + k * 4 + j] = wg;
            s += wg; c += nd_be[k] * w;
        }
        ws[WS_SN3 + j] = s;
        ws[WS_CN3 + j] = c + nd_b2[j];
    }
}

// ---------------------------------------------------------------------------
// Kernel A: per-graph work. 1024 blocks x 128 threads.
//  P1b (bias folded), P2, ZW = z_proj@nd_w1 + Cn1, energy/stress heads
// ---------------------------------------------------------------------------
__global__ __launch_bounds__(128) void graph_kernel(
    const float* __restrict__ z,
    const float* __restrict__ lp_w, const float* __restrict__ lp_b,
    const float* __restrict__ lp_g, const float* __restrict__ lp_be,
    const float* __restrict__ ed_w1, const float* __restrict__ ed_b1,
    const float* __restrict__ nd_w1,
    const float* __restrict__ en_w1, const float* __restrict__ en_b1,
    const float* __restrict__ en_g,  const float* __restrict__ en_be,
    const float* __restrict__ en_w2, const float* __restrict__ en_b2,
    const float* __restrict__ st_w1, const float* __restrict__ st_b1,
    const float* __restrict__ st_g,  const float* __restrict__ st_be,
    const float* __restrict__ st_w2, const float* __restrict__ st_b2,
    float* __restrict__ ws,
    float* __restrict__ out_pe, float* __restrict__ out_ps)
{
    const int b = blockIdx.x;
    const int t = threadIdx.x;
    __shared__ float zrow[32];
    __shared__ float zp[128];
    __shared__ float red[2];
    __shared__ float eh[64];
    __shared__ float sh[64];

    if (t < 32) zrow[t] = z[b * 32 + t];
    __syncthreads();

    // latent_proj: Linear(32,128) -> GELU -> LN(128)
    float acc = lp_b[t];
    #pragma unroll
    for (int k = 0; k < 32; ++k) acc += zrow[k] * lp_w[k * 128 + t];
    acc = gelu_f(acc);

    float s = acc;
    #pragma unroll
    for (int o = 32; o >= 1; o >>= 1) s += __shfl_xor(s, o, 64);
    if ((t & 63) == 0) red[t >> 6] = s;
    __syncthreads();
    float mu = (red[0] + red[1]) * (1.0f / 128.0f);
    __syncthreads();
    float d = acc - mu;
    s = d * d;
    #pragma unroll
    for (int o = 32; o >= 1; o >>= 1) s += __shfl_xor(s, o, 64);
    if ((t & 63) == 0) red[t >> 6] = s;
    __syncthreads();
    float var = (red[0] + red[1]) * (1.0f / 128.0f);
    float v = d * rsqrtf(var + 1e-5f) * lp_g[t] + lp_be[t];
    zp[t] = v;
    __syncthreads();

    // P1b / P2 rows (edge layer-1 precompute)
    float a1 = ed_b1[t], a2 = 0.0f;
    #pragma unroll 4
    for (int k = 0; k < 128; ++k) {
        const float zv = zp[k];
        a1 += zv * ed_w1[k * 128 + t];
        a2 += zv * ed_w1[(k + 128) * 128 + t];
    }
    ws[WS_P1B + b * 128 + t] = a1;
    ws[WS_P2  + b * 128 + t] = a2;

    // ZW row: z_proj[b] @ nd_w1 + Cn1  (node layer-2 z-contribution)
    if (t < 64) {
        float a = ws[WS_CN1 + t];
        #pragma unroll 4
        for (int k = 0; k < 128; ++k) a += zp[k] * nd_w1[k * 64 + t];
        ws[WS_ZW + b * 64 + t] = a;
    }

    // heads: wave0 -> energy, wave1 -> stress
    {
        const int lane = t & 63;
        const bool en = (t < 64);
        const float* w1 = en ? en_w1 : st_w1;
        const float* b1 = en ? en_b1 : st_b1;
        const float* g  = en ? en_g  : st_g;
        const float* be = en ? en_be : st_be;
        float h = b1[lane];
        #pragma unroll
        for (int k = 0; k < 32; ++k) h += zrow[k] * w1[k * 64 + lane];
        h = gelu_f(h);
        float m = h;
        #pragma unroll
        for (int o = 32; o >= 1; o >>= 1) m += __shfl_xor(m, o, 64);
        m *= (1.0f / 64.0f);
        float dd = h - m;
        float vv = dd * dd;
        #pragma unroll
        for (int o = 32; o >= 1; o >>= 1) vv += __shfl_xor(vv, o, 64);
        vv *= (1.0f / 64.0f);
        float hn = dd * rsqrtf(vv + 1e-5f) * g[lane] + be[lane];
        if (en) eh[lane] = hn; else sh[lane] = hn;
    }
    __syncthreads();
    if (t < 2) {
        float a = en_b2[t];
        for (int j = 0; j < 64; ++j) a += eh[j] * en_w2[j * 2 + t];
        out_pe[b * 2 + t] = a;
    }
    if (t >= 64 && t < 73) {
        const int c = t - 64;
        float a = st_b2[c];
        for (int j = 0; j < 64; ++j) a += sh[j] * st_w2[j * 9 + c];
        out_ps[b * 9 + c] = a;
    }
}

// ---------------------------------------------------------------------------
// Kernel B: fused node path. 3200 blocks x 256 threads, 64 nodes/block.
// tr = t>>4 owns rows {tr+16i, i<4}; rows wave-private after the one barrier.
// LN1 folded into WG1N/SN + ZW table; LN2 folded into WN3G/SN3/CN3.
// ---------------------------------------------------------------------------
__global__ __launch_bounds__(256, 4) void node_kernel(
    const float* __restrict__ node_emb, const int* __restrict__ n2g,
    const float* __restrict__ ne_w, const float* __restrict__ ne_b,
    const float* __restrict__ ws,
    float* __restrict__ out_node)
{
    __shared__ float tile[64][132];
    __shared__ int gidx[64];
    const int t = threadIdx.x;
    const int node0 = blockIdx.x * 64;

    if (t < 64) gidx[t] = n2g[node0 + t];
    // stage node_emb tile [64][128]
    {
        const int r0 = t >> 5;
        const int c4 = (t & 31) * 4;
        #pragma unroll
        for (int m = 0; m < 8; ++m) {
            const int rr = r0 + m * 8;
            *(float4*)&tile[rr][c4] =
                *(const float4*)(node_emb + (size_t)(node0 + rr) * 128 + c4);
        }
    }
    __syncthreads();

    const int tr = t >> 4;
    const int tc = t & 15;

    // ---- layer 1: emb[64,128] @ ne_w[128,128], 4 rows x 8 cols/thread ----
    float acc[4][8];
    #pragma unroll
    for (int i = 0; i < 4; ++i)
        #pragma unroll
        for (int j = 0; j < 8; ++j) acc[i][j] = 0.0f;

    for (int k4 = 0; k4 < 128; k4 += 4) {
        float w[4][8];
        #pragma unroll
        for (int kk = 0; kk < 4; ++kk) {
            float4 wa = *(const float4*)(ne_w + (size_t)(k4 + kk) * 128 + tc * 8);
            float4 wb = *(const float4*)(ne_w + (size_t)(k4 + kk) * 128 + tc * 8 + 4);
            w[kk][0] = wa.x; w[kk][1] = wa.y; w[kk][2] = wa.z; w[kk][3] = wa.w;
            w[kk][4] = wb.x; w[kk][5] = wb.y; w[kk][6] = wb.z; w[kk][7] = wb.w;
        }
        #pragma unroll
        for (int i = 0; i < 4; ++i) {
            float4 iv = *(const float4*)&tile[tr + 16 * i][k4];
            float in4[4] = {iv.x, iv.y, iv.z, iv.w};
            #pragma unroll
            for (int kk = 0; kk < 4; ++kk)
                #pragma unroll
                for (int j = 0; j < 8; ++j)
                    acc[i][j] += in4[kk] * w[kk][j];
        }
    }

    // y = gelu(acc + ne_b); per-row mu/rstd from registers; write raw y to tile
    float mu1[4], rs1[4];
    {
        float4 b0 = *(const float4*)(ne_b + tc * 8);
        float4 b1 = *(const float4*)(ne_b + tc * 8 + 4);
        float nb[8] = {b0.x,b0.y,b0.z,b0.w,b1.x,b1.y,b1.z,b1.w};
        #pragma unroll
        for (int i = 0; i < 4; ++i) {
            const int r = tr + 16 * i;
            float y[8];
            float ssum = 0.0f, ssq = 0.0f;
            #pragma unroll
            for (int j = 0; j < 8; ++j) {
                y[j] = gelu_f(acc[i][j] + nb[j]);
                ssum += y[j]; ssq += y[j] * y[j];
            }
            #pragma unroll
            for (int o = 1; o < 16; o <<= 1) {
                ssum += __shfl_xor(ssum, o, 64);
                ssq  += __shfl_xor(ssq,  o, 64);
            }
            const float m = ssum * (1.0f / 128.0f);
            mu1[i] = m;
            rs1[i] = rsqrtf(ssq * (1.0f / 128.0f) - m * m + 1e-5f);
            float4 o0 = {y[0], y[1], y[2], y[3]};
            float4 o1 = {y[4], y[5], y[6], y[7]};
            *(float4*)&tile[r][tc * 8]     = o0;
            *(float4*)&tile[r][tc * 8 + 4] = o1;
        }
    }
    // rows wave-private -> no barrier

    // ---- layer 2 (LN folded): pre = rs*(y@WG1N - mu*SN) + ZW[g] ----
    float acc2[4][4];
    #pragma unroll
    for (int i = 0; i < 4; ++i)
        #pragma unroll
        for (int j = 0; j < 4; ++j) acc2[i][j] = 0.0f;

    const float* wg1 = ws + WS_WG1N;
    for (int k4 = 0; k4 < 128; k4 += 4) {
        float w2[4][4];
        #pragma unroll
        for (int kk = 0; kk < 4; ++kk) {
            float4 wv = *(const float4*)(wg1 + (size_t)(k4 + kk) * 64 + tc * 4);
            w2[kk][0] = wv.x; w2[kk][1] = wv.y; w2[kk][2] = wv.z; w2[kk][3] = wv.w;
        }
        #pragma unroll
        for (int i = 0; i < 4; ++i) {
            float4 iv = *(const float4*)&tile[tr + 16 * i][k4];
            float in4[4] = {iv.x, iv.y, iv.z, iv.w};
            #pragma unroll
            for (int kk = 0; kk < 4; ++kk)
                #pragma unroll
                for (int j = 0; j < 4; ++j)
                    acc2[i][j] += in4[kk] * w2[kk][j];
        }
    }

    // epilogue: u = gelu(pre); out = rs2*(u@WN3G - mu2*SN3) + CN3
    {
        float4 snv = *(const float4*)(ws + WS_SN + tc * 4);
        float sn[4] = {snv.x, snv.y, snv.z, snv.w};
        float w3[4][4];
        #pragma unroll
        for (int j = 0; j < 4; ++j) {
            float4 wv = *(const float4*)(ws + WS_WN3G + (size_t)(tc * 4 + j) * 4);
            w3[j][0] = wv.x; w3[j][1] = wv.y; w3[j][2] = wv.z; w3[j][3] = wv.w;
        }
        const float sn3 = ws[WS_SN3 + tc] ;
        const float cn3 = ws[WS_CN3 + tc];
        #pragma unroll
        for (int i = 0; i < 4; ++i) {
            const int node = tr + 16 * i;
            const int g = gidx[node];
            float4 zwv = *(const float4*)(ws + WS_ZW + (size_t)g * 64 + tc * 4);
            float zw[4] = {zwv.x, zwv.y, zwv.z, zwv.w};
            float u[4];
            float ssum = 0.0f, ssq = 0.0f;
            #pragma unroll
            for (int j = 0; j < 4; ++j) {
                const float pre = rs1[i] * (acc2[i][j] - mu1[i] * sn[j]) + zw[j];
                u[j] = gelu_f(pre);
                ssum += u[j]; ssq += u[j] * u[j];
            }
            #pragma unroll
            for (int o = 1; o < 16; o <<= 1) {
                ssum += __shfl_xor(ssum, o, 64);
                ssq  += __shfl_xor(ssq,  o, 64);
            }
            const float m2 = ssum * (1.0f / 64.0f);
            const float rs2 = rsqrtf(ssq * (1.0f / 64.0f) - m2 * m2 + 1e-5f);
            float p[4] = {0.0f, 0.0f, 0.0f, 0.0f};
            #pragma unroll
            for (int j = 0; j < 4; ++j)
                #pragma unroll
                for (int c = 0; c < 4; ++c) p[c] += u[j] * w3[j][c];
            #pragma unroll
            for (int c = 0; c < 4; ++c)
                #pragma unroll
                for (int o = 1; o < 16; o <<= 1) p[c] += __shfl_xor(p[c], o, 64);
            float r = p[0];
            if (tc == 1) r = p[1];
            else if (tc == 2) r = p[2];
            else if (tc == 3) r = p[3];
            if (tc < 4)
                out_node[(size_t)(node0 + node) * 4 + tc] =
                    rs2 * (r - m2 * sn3) + cn3;
        }
    }
}

// ---------------------------------------------------------------------------
// Kernel C: fused edge path. 15625 blocks x 256 threads, 64 edges/block.
// stage = gelu(P1b[gs]+P2[gd]) raw into LDS; LN1 folded into WG2E/SE/C1E;
// LN2 folded into W3GE/S3E/C3E.
// ---------------------------------------------------------------------------
__global__ __launch_bounds__(256, 4) void edge_kernel(
    const int* __restrict__ src, const int* __restrict__ dst,
    const int* __restrict__ n2g,
    const float* __restrict__ ws,
    float* __restrict__ out_edge)
{
    __shared__ float tile[64][132];
    __shared__ int gsrc[64];
    __shared__ int gdst[64];
    const int t = threadIdx.x;
    const int e0 = blockIdx.x * 64;

    if (t < 64) {
        gsrc[t] = n2g[src[e0 + t]];
        gdst[t] = n2g[dst[e0 + t]];
    }
    __syncthreads();

    // stage y = gelu(P1b[gs] + P2[gd]) (raw, no LN)
    {
        const int r0 = t >> 5;
        const int c4 = (t & 31) * 4;
        #pragma unroll
        for (int m = 0; m < 8; ++m) {
            const int rr = r0 + m * 8;
            const float4 a = *(const float4*)(ws + WS_P1B + (size_t)gsrc[rr] * 128 + c4);
            const float4 b = *(const float4*)(ws + WS_P2  + (size_t)gdst[rr] * 128 + c4);
            float4 y;
            y.x = gelu_f(a.x + b.x);
            y.y = gelu_f(a.y + b.y);
            y.z = gelu_f(a.z + b.z);
            y.w = gelu_f(a.w + b.w);
            *(float4*)&tile[rr][c4] = y;
        }
    }
    __syncthreads();

    const int tr = t >> 4;
    const int tc = t & 15;

    // per-row mu/rstd over raw y (read-only pass, no writeback)
    float mu1[4], rs1[4];
    #pragma unroll
    for (int i = 0; i < 4; ++i) {
        const int r = tr + 16 * i;
        float4 x0 = *(const float4*)&tile[r][tc * 8];
        float4 x1 = *(const float4*)&tile[r][tc * 8 + 4];
        float ssum = x0.x + x0.y + x0.z + x0.w + x1.x + x1.y + x1.z + x1.w;
        float ssq  = x0.x*x0.x + x0.y*x0.y + x0.z*x0.z + x0.w*x0.w
                   + x1.x*x1.x + x1.y*x1.y + x1.z*x1.z + x1.w*x1.w;
        #pragma unroll
        for (int o = 1; o < 16; o <<= 1) {
            ssum += __shfl_xor(ssum, o, 64);
            ssq  += __shfl_xor(ssq,  o, 64);
        }
        const float m = ssum * (1.0f / 128.0f);
        mu1[i] = m;
        rs1[i] = rsqrtf(ssq * (1.0f / 128.0f) - m * m + 1e-5f);
    }

    // ---- layer 2 (LN folded): pre = rs*(y@WG2E - mu*SE) + C1E ----
    float acc2[4][4];
    #pragma unroll
    for (int i = 0; i < 4; ++i)
        #pragma unroll
        for (int j = 0; j < 4; ++j) acc2[i][j] = 0.0f;

    const float* wg2 = ws + WS_WG2E;
    for (int k4 = 0; k4 < 128; k4 += 4) {
        float w2[4][4];
        #pragma unroll
        for (int kk = 0; kk < 4; ++kk) {
            float4 wv = *(const float4*)(wg2 + (size_t)(k4 + kk) * 64 + tc * 4);
            w2[kk][0] = wv.x; w2[kk][1] = wv.y; w2[kk][2] = wv.z; w2[kk][3] = wv.w;
        }
        #pragma unroll
        for (int i = 0; i < 4; ++i) {
            float4 iv = *(const float4*)&tile[tr + 16 * i][k4];
            float in4[4] = {iv.x, iv.y, iv.z, iv.w};
            #pragma unroll
            for (int kk = 0; kk < 4; ++kk)
                #pragma unroll
                for (int j = 0; j < 4; ++j)
                    acc2[i][j] += in4[kk] * w2[kk][j];
        }
    }

    // epilogue: u = gelu(pre); out = rs2*(u@W3GE - mu2*S3E) + C3E
    {
        float4 sev = *(const float4*)(ws + WS_SE + tc * 4);
        float se[4] = {sev.x, sev.y, sev.z, sev.w};
        float4 c1v = *(const float4*)(ws + WS_C1E + tc * 4);
        float c1[4] = {c1v.x, c1v.y, c1v.z, c1v.w};
        float w3[4][3];
        #pragma unroll
        for (int j = 0; j < 4; ++j) {
            const float* wp = ws + WS_W3GE + (size_t)(tc * 4 + j) * 3;
            w3[j][0] = wp[0]; w3[j][1] = wp[1]; w3[j][2] = wp[2];
        }
        const int cidx = (tc < 3) ? tc : 0;
        const float s3 = ws[WS_S3E + cidx];
        const float c3 = ws[WS_C3E + cidx];
        #pragma unroll
        for (int i = 0; i < 4; ++i) {
            const int e = e0 + tr + 16 * i;
            float u[4];
            float ssum = 0.0f, ssq = 0.0f;
            #pragma unroll
            for (int j = 0; j < 4; ++j) {
                const float pre = rs1[i] * (acc2[i][j] - mu1[i] * se[j]) + c1[j];
                u[j] = gelu_f(pre);
                ssum += u[j]; ssq += u[j] * u[j];
            }
            #pragma unroll
            for (int o = 1; o < 16; o <<= 1) {
                ssum += __shfl_xor(ssum, o, 64);
                ssq  += __shfl_xor(ssq,  o, 64);
            }
            const float m2 = ssum * (1.0f / 64.0f);
            const float rs2 = rsqrtf(ssq * (1.0f / 64.0f) - m2 * m2 + 1e-5f);
            float p[3] = {0.0f, 0.0f, 0.0f};
            #pragma unroll
            for (int j = 0; j < 4; ++j)
                #pragma unroll
                for (int c = 0; c < 3; ++c) p[c] += u[j] * w3[j][c];
            #pragma unroll
            for (int c = 0; c < 3; ++c)
                #pragma unroll
                for (int o = 1; o < 16; o <<= 1) p[c] += __shfl_xor(p[c], o, 64);
            float r = p[0];
            if (tc == 1) r = p[1];
            else if (tc == 2) r = p[2];
            if (tc < 3)
                out_edge[(size_t)e * 3 + tc] = rs2 * (r - m2 * s3) + c3;
        }
    }
}

extern "C" void kernel_launch(void* const* d_in, const int* in_sizes, int n_in,
                              void* d_out, int out_size, void* d_ws, size_t ws_size,
                              hipStream_t stream) {
    const float* z        = (const float*)d_in[0];
    const float* node_emb = (const float*)d_in[1];
    const int*   n2g      = (const int*)d_in[2];
    const int*   src      = (const int*)d_in[3];
    const int*   dst      = (const int*)d_in[4];
    const float* lp_w  = (const float*)d_in[5];
    const float* lp_b  = (const float*)d_in[6];
    const float* lp_g  = (const float*)d_in[7];
    const float* lp_be = (const float*)d_in[8];
    const float* ne_w  = (const float*)d_in[9];
    const float* ne_b  = (const float*)d_in[10];
    const float* ne_g  = (const float*)d_in[11];
    const float* ne_be = (const float*)d_in[12];
    const float* nd_w1 = (const float*)d_in[13];
    const float* nd_b1 = (const float*)d_in[14];
    const float* nd_g  = (const float*)d_in[15];
    const float* nd_be = (const float*)d_in[16];
    const float* nd_w2 = (const float*)d_in[17];
    const float* nd_b2 = (const float*)d_in[18];
    const float* ed_w1 = (const float*)d_in[19];
    const float* ed_b1 = (const float*)d_in[20];
    const float* ed_g1 = (const float*)d_in[21];
    const float* ed_be1= (const float*)d_in[22];
    const float* ed_w2 = (const float*)d_in[23];
    const float* ed_b2 = (const float*)d_in[24];
    const float* ed_g2 = (const float*)d_in[25];
    const float* ed_be2= (const float*)d_in[26];
    const float* ed_w3 = (const float*)d_in[27];
    const float* ed_b3 = (const float*)d_in[28];
    const float* en_w1 = (const float*)d_in[29];
    const float* en_b1 = (const float*)d_in[30];
    const float* en_g  = (const float*)d_in[31];
    const float* en_be = (const float*)d_in[32];
    const float* en_w2 = (const float*)d_in[33];
    const float* en_b2 = (const float*)d_in[34];
    const float* st_w1 = (const float*)d_in[35];
    const float* st_b1 = (const float*)d_in[36];
    const float* st_g  = (const float*)d_in[37];
    const float* st_be = (const float*)d_in[38];
    const float* st_w2 = (const float*)d_in[39];
    const float* st_b2 = (const float*)d_in[40];

    float* out       = (float*)d_out;
    float* out_node  = out;                                   // N*4
    float* out_edge  = out + (size_t)NN * 4;                  // E*3
    float* out_pe    = out + (size_t)NN * 4 + (size_t)NE * 3; // B*2
    float* out_ps    = out_pe + (size_t)NB * 2;               // B*9

    float* ws = (float*)d_ws;

    prep_kernel<<<1, 256, 0, stream>>>(
        ed_g1, ed_be1, ed_w2, ed_b2, ed_g2, ed_be2, ed_w3, ed_b3,
        ne_g, ne_be, nd_w1, nd_b1, nd_g, nd_be, nd_w2, nd_b2, ws);

    graph_kernel<<<NB, 128, 0, stream>>>(
        z, lp_w, lp_b, lp_g, lp_be, ed_w1, ed_b1, nd_w1,
        en_w1, en_b1, en_g, en_be, en_w2, en_b2,
        st_w1, st_b1, st_g, st_be, st_w2, st_b2,
        ws, out_pe, out_ps);

    node_kernel<<<NN / 64, 256, 0, stream>>>(
        node_emb, n2g, ne_w, ne_b, ws, out_node);

    edge_kernel<<<NE / 64, 256, 0, stream>>>(
        src, dst, n2g, ws, out_edge);
}

// Round 7
// 776.782 us; speedup vs baseline: 1.2613x; 1.0034x over previous
//
#include <hip/hip_runtime.h>
#include <hip/hip_bf16.h>
#include <math.h>

#define NB 1024
#define NN 204800
#define NE 1000000

typedef _Float16 h4 __attribute__((ext_vector_type(4)));
typedef _Float16 h8 __attribute__((ext_vector_type(8)));

// Branch-free GELU(x) = x * Phi(x); erf via Abramowitz-Stegun 7.1.26 (|err|<=1.5e-7)
__device__ __forceinline__ float gelu_f(float x) {
    const float a = fabsf(x) * 0.70710678118654752f;
    const float t = __builtin_amdgcn_rcpf(1.0f + 0.3275911f * a);
    const float poly = t * (0.254829592f + t * (-0.284496736f +
                       t * (1.421413741f + t * (-1.453152027f + t * 1.061405429f))));
    const float e = __expf(-a * a);
    const float erf_a = 1.0f - poly * e;
    return x * (0.5f + 0.5f * copysignf(erf_a, x));
}

// ---------------------------------------------------------------------------
// ws layout (floats, offsets)
// ---------------------------------------------------------------------------
#define WS_P1B   131072    // 1024*128
#define WS_P2    262144    // 1024*128
#define WS_ZW    393216    // 1024*64
#define WS_WG2E  458752    // 128*64   (ed_g1 * ed_w2)
#define WS_WG1N  466944    // 128*64   (ne_g * nd_w1)
#define WS_SE    475136    // 64       colsum(WG2E)
#define WS_C1E   475200    // 64       ed_be1@ed_w2 + ed_b2
#define WS_SN    475264    // 64       colsum(WG1N)
#define WS_CN1   475328    // 64       ne_be@nd_w1 + nd_b1
#define WS_W3GE  475392    // 64*3     (ed_g2 * ed_w3)
#define WS_S3E   475584    // 3
#define WS_C3E   475648    // 3        ed_be2@ed_w3 + ed_b3
#define WS_WN3G  475712    // 64*4     (nd_g * nd_w2)
#define WS_SN3   475968    // 4
#define WS_CN3   476032    // 4        nd_be@nd_w2 + nd_b2

// ---------------------------------------------------------------------------
// Prep kernel: build LN-folded weight tables. 1 block x 256 threads.
// ---------------------------------------------------------------------------
__global__ __launch_bounds__(256) void prep_kernel(
    const float* __restrict__ ed_g1, const float* __restrict__ ed_be1,
    const float* __restrict__ ed_w2, const float* __restrict__ ed_b2,
    const float* __restrict__ ed_g2, const float* __restrict__ ed_be2,
    const float* __restrict__ ed_w3, const float* __restrict__ ed_b3,
    const float* __restrict__ ne_g,  const float* __restrict__ ne_be,
    const float* __restrict__ nd_w1, const float* __restrict__ nd_b1,
    const float* __restrict__ nd_g,  const float* __restrict__ nd_be,
    const float* __restrict__ nd_w2, const float* __restrict__ nd_b2,
    float* __restrict__ ws)
{
    const int t = threadIdx.x;
    if (t < 64) {                       // edge W2 fold, column j
        const int j = t;
        float s = 0.0f, c = 0.0f;
        for (int k = 0; k < 128; ++k) {
            const float w = ed_w2[k * 64 + j];
            const float wg = ed_g1[k] * w;
            ws[WS_WG2E + k * 64 + j] = wg;
            s += wg; c += ed_be1[k] * w;
        }
        ws[WS_SE + j] = s;
        ws[WS_C1E + j] = c + ed_b2[j];
    } else if (t < 128) {               // node W1 fold, column j
        const int j = t - 64;
        float s = 0.0f, c = 0.0f;
        for (int k = 0; k < 128; ++k) {
            const float w = nd_w1[k * 64 + j];
            const float wg = ne_g[k] * w;
            ws[WS_WG1N + k * 64 + j] = wg;
            s += wg; c += ne_be[k] * w;
        }
        ws[WS_SN + j] = s;
        ws[WS_CN1 + j] = c + nd_b1[j];
    } else if (t < 131) {               // edge W3 fold
        const int j = t - 128;
        float s = 0.0f, c = 0.0f;
        for (int k = 0; k < 64; ++k) {
            const float w = ed_w3[k * 3 + j];
            const float wg = ed_g2[k] * w;
            ws[WS_W3GE + k * 3 + j] = wg;
            s += wg; c += ed_be2[k] * w;
        }
        ws[WS_S3E + j] = s;
        ws[WS_C3E + j] = c + ed_b3[j];
    } else if (t < 135) {               // node W3 fold
        const int j = t - 131;
        float s = 0.0f, c = 0.0f;
        for (int k = 0; k < 64; ++k) {
            const float w = nd_w2[k * 4 + j];
            const float wg = nd_g[k] * w;
            ws[WS_WN3G + k * 4 + j] = wg;
            s += wg; c += nd_be[k] * w;
        }
        ws[WS_SN3 + j] = s;
        ws[WS_CN3 + j] = c + nd_b2[j];
    }
}

// ---------------------------------------------------------------------------
// Kernel A: per-graph work. 1024 blocks x 128 threads.
// ---------------------------------------------------------------------------
__global__ __launch_bounds__(128) void graph_kernel(
    const float* __restrict__ z,
    const float* __restrict__ lp_w, const float* __restrict__ lp_b,
    const float* __restrict__ lp_g, const float* __restrict__ lp_be,
    const float* __restrict__ ed_w1, const float* __restrict__ ed_b1,
    const float* __restrict__ nd_w1,
    const float* __restrict__ en_w1, const float* __restrict__ en_b1,
    const float* __restrict__ en_g,  const float* __restrict__ en_be,
    const float* __restrict__ en_w2, const float* __restrict__ en_b2,
    const float* __restrict__ st_w1, const float* __restrict__ st_b1,
    const float* __restrict__ st_g,  const float* __restrict__ st_be,
    const float* __restrict__ st_w2, const float* __restrict__ st_b2,
    float* __restrict__ ws,
    float* __restrict__ out_pe, float* __restrict__ out_ps)
{
    const int b = blockIdx.x;
    const int t = threadIdx.x;
    __shared__ float zrow[32];
    __shared__ float zp[128];
    __shared__ float red[2];
    __shared__ float eh[64];
    __shared__ float sh[64];

    if (t < 32) zrow[t] = z[b * 32 + t];
    __syncthreads();

    float acc = lp_b[t];
    #pragma unroll
    for (int k = 0; k < 32; ++k) acc += zrow[k] * lp_w[k * 128 + t];
    acc = gelu_f(acc);

    float s = acc;
    #pragma unroll
    for (int o = 32; o >= 1; o >>= 1) s += __shfl_xor(s, o, 64);
    if ((t & 63) == 0) red[t >> 6] = s;
    __syncthreads();
    float mu = (red[0] + red[1]) * (1.0f / 128.0f);
    __syncthreads();
    float d = acc - mu;
    s = d * d;
    #pragma unroll
    for (int o = 32; o >= 1; o >>= 1) s += __shfl_xor(s, o, 64);
    if ((t & 63) == 0) red[t >> 6] = s;
    __syncthreads();
    float var = (red[0] + red[1]) * (1.0f / 128.0f);
    float v = d * rsqrtf(var + 1e-5f) * lp_g[t] + lp_be[t];
    zp[t] = v;
    __syncthreads();

    float a1 = ed_b1[t], a2 = 0.0f;
    #pragma unroll 4
    for (int k = 0; k < 128; ++k) {
        const float zv = zp[k];
        a1 += zv * ed_w1[k * 128 + t];
        a2 += zv * ed_w1[(k + 128) * 128 + t];
    }
    ws[WS_P1B + b * 128 + t] = a1;
    ws[WS_P2  + b * 128 + t] = a2;

    if (t < 64) {
        float a = ws[WS_CN1 + t];
        #pragma unroll 4
        for (int k = 0; k < 128; ++k) a += zp[k] * nd_w1[k * 64 + t];
        ws[WS_ZW + b * 64 + t] = a;
    }

    {
        const int lane = t & 63;
        const bool en = (t < 64);
        const float* w1 = en ? en_w1 : st_w1;
        const float* b1 = en ? en_b1 : st_b1;
        const float* g  = en ? en_g  : st_g;
        const float* be = en ? en_be : st_be;
        float h = b1[lane];
        #pragma unroll
        for (int k = 0; k < 32; ++k) h += zrow[k] * w1[k * 64 + lane];
        h = gelu_f(h);
        float m = h;
        #pragma unroll
        for (int o = 32; o >= 1; o >>= 1) m += __shfl_xor(m, o, 64);
        m *= (1.0f / 64.0f);
        float dd = h - m;
        float vv = dd * dd;
        #pragma unroll
        for (int o = 32; o >= 1; o >>= 1) vv += __shfl_xor(vv, o, 64);
        vv *= (1.0f / 64.0f);
        float hn = dd * rsqrtf(vv + 1e-5f) * g[lane] + be[lane];
        if (en) eh[lane] = hn; else sh[lane] = hn;
    }
    __syncthreads();
    if (t < 2) {
        float a = en_b2[t];
        for (int j = 0; j < 64; ++j) a += eh[j] * en_w2[j * 2 + t];
        out_pe[b * 2 + t] = a;
    }
    if (t >= 64 && t < 73) {
        const int c = t - 64;
        float a = st_b2[c];
        for (int j = 0; j < 64; ++j) a += sh[j] * st_w2[j * 9 + c];
        out_ps[b * 9 + c] = a;
    }
}

// ---------------------------------------------------------------------------
// Kernel B: fused node path. 3200 blocks x 256 threads, 64 nodes/block.
// f16 LDS tile (17.9 KB -> 8 blocks/CU); all arithmetic fp32.
// tr = t>>4 owns rows {tr+16i}; rows wave-private after the one barrier.
// ---------------------------------------------------------------------------
__global__ __launch_bounds__(256, 4) void node_kernel(
    const float* __restrict__ node_emb, const int* __restrict__ n2g,
    const float* __restrict__ ne_w, const float* __restrict__ ne_b,
    const float* __restrict__ ws,
    float* __restrict__ out_node)
{
    __shared__ _Float16 tile[64][136];   // 136-half stride: 272B, 16B-aligned rows
    __shared__ int gidx[64];
    const int t = threadIdx.x;
    const int node0 = blockIdx.x * 64;

    if (t < 64) gidx[t] = n2g[node0 + t];
    // stage node_emb tile [64][128] as f16
    {
        const int r0 = t >> 5;
        const int c4 = (t & 31) * 4;
        #pragma unroll
        for (int m = 0; m < 8; ++m) {
            const int rr = r0 + m * 8;
            float4 v = *(const float4*)(node_emb + (size_t)(node0 + rr) * 128 + c4);
            h4 hv;
            hv[0] = (_Float16)v.x; hv[1] = (_Float16)v.y;
            hv[2] = (_Float16)v.z; hv[3] = (_Float16)v.w;
            *(h4*)&tile[rr][c4] = hv;
        }
    }
    __syncthreads();

    const int tr = t >> 4;
    const int tc = t & 15;

    // ---- layer 1: emb[64,128] @ ne_w[128,128], 4 rows x 8 cols/thread ----
    float acc[4][8];
    #pragma unroll
    for (int i = 0; i < 4; ++i)
        #pragma unroll
        for (int j = 0; j < 8; ++j) acc[i][j] = 0.0f;

    for (int k4 = 0; k4 < 128; k4 += 4) {
        float w[4][8];
        #pragma unroll
        for (int kk = 0; kk < 4; ++kk) {
            float4 wa = *(const float4*)(ne_w + (size_t)(k4 + kk) * 128 + tc * 8);
            float4 wb = *(const float4*)(ne_w + (size_t)(k4 + kk) * 128 + tc * 8 + 4);
            w[kk][0] = wa.x; w[kk][1] = wa.y; w[kk][2] = wa.z; w[kk][3] = wa.w;
            w[kk][4] = wb.x; w[kk][5] = wb.y; w[kk][6] = wb.z; w[kk][7] = wb.w;
        }
        #pragma unroll
        for (int i = 0; i < 4; ++i) {
            h4 hv = *(const h4*)&tile[tr + 16 * i][k4];
            float in4[4] = {(float)hv[0], (float)hv[1], (float)hv[2], (float)hv[3]};
            #pragma unroll
            for (int kk = 0; kk < 4; ++kk)
                #pragma unroll
                for (int j = 0; j < 8; ++j)
                    acc[i][j] += in4[kk] * w[kk][j];
        }
    }

    // y = gelu(acc + ne_b), rounded to f16; stats over the rounded values;
    // rounded y written back to tile (stats/GEMM see identical values)
    float mu1[4], rs1[4];
    {
        float4 b0 = *(const float4*)(ne_b + tc * 8);
        float4 b1 = *(const float4*)(ne_b + tc * 8 + 4);
        float nb[8] = {b0.x,b0.y,b0.z,b0.w,b1.x,b1.y,b1.z,b1.w};
        #pragma unroll
        for (int i = 0; i < 4; ++i) {
            const int r = tr + 16 * i;
            float y[8];
            float ssum = 0.0f, ssq = 0.0f;
            #pragma unroll
            for (int j = 0; j < 8; ++j) {
                y[j] = (float)(_Float16)gelu_f(acc[i][j] + nb[j]);
                ssum += y[j]; ssq += y[j] * y[j];
            }
            #pragma unroll
            for (int o = 1; o < 16; o <<= 1) {
                ssum += __shfl_xor(ssum, o, 64);
                ssq  += __shfl_xor(ssq,  o, 64);
            }
            const float m = ssum * (1.0f / 128.0f);
            mu1[i] = m;
            rs1[i] = rsqrtf(ssq * (1.0f / 128.0f) - m * m + 1e-5f);
            h4 o0, o1;
            o0[0] = (_Float16)y[0]; o0[1] = (_Float16)y[1];
            o0[2] = (_Float16)y[2]; o0[3] = (_Float16)y[3];
            o1[0] = (_Float16)y[4]; o1[1] = (_Float16)y[5];
            o1[2] = (_Float16)y[6]; o1[3] = (_Float16)y[7];
            *(h4*)&tile[r][tc * 8]     = o0;
            *(h4*)&tile[r][tc * 8 + 4] = o1;
        }
    }
    // rows wave-private -> no barrier

    // ---- layer 2 (LN folded): pre = rs*(y@WG1N - mu*SN) + ZW[g] ----
    float acc2[4][4];
    #pragma unroll
    for (int i = 0; i < 4; ++i)
        #pragma unroll
        for (int j = 0; j < 4; ++j) acc2[i][j] = 0.0f;

    const float* wg1 = ws + WS_WG1N;
    for (int k4 = 0; k4 < 128; k4 += 4) {
        float w2[4][4];
        #pragma unroll
        for (int kk = 0; kk < 4; ++kk) {
            float4 wv = *(const float4*)(wg1 + (size_t)(k4 + kk) * 64 + tc * 4);
            w2[kk][0] = wv.x; w2[kk][1] = wv.y; w2[kk][2] = wv.z; w2[kk][3] = wv.w;
        }
        #pragma unroll
        for (int i = 0; i < 4; ++i) {
            h4 hv = *(const h4*)&tile[tr + 16 * i][k4];
            float in4[4] = {(float)hv[0], (float)hv[1], (float)hv[2], (float)hv[3]};
            #pragma unroll
            for (int kk = 0; kk < 4; ++kk)
                #pragma unroll
                for (int j = 0; j < 4; ++j)
                    acc2[i][j] += in4[kk] * w2[kk][j];
        }
    }

    // epilogue: u = gelu(pre); out = rs2*(u@WN3G - mu2*SN3) + CN3
    {
        float4 snv = *(const float4*)(ws + WS_SN + tc * 4);
        float sn[4] = {snv.x, snv.y, snv.z, snv.w};
        float w3[4][4];
        #pragma unroll
        for (int j = 0; j < 4; ++j) {
            float4 wv = *(const float4*)(ws + WS_WN3G + (size_t)(tc * 4 + j) * 4);
            w3[j][0] = wv.x; w3[j][1] = wv.y; w3[j][2] = wv.z; w3[j][3] = wv.w;
        }
        const float sn3 = ws[WS_SN3 + tc];
        const float cn3 = ws[WS_CN3 + tc];
        #pragma unroll
        for (int i = 0; i < 4; ++i) {
            const int node = tr + 16 * i;
            const int g = gidx[node];
            float4 zwv = *(const float4*)(ws + WS_ZW + (size_t)g * 64 + tc * 4);
            float zw[4] = {zwv.x, zwv.y, zwv.z, zwv.w};
            float u[4];
            float ssum = 0.0f, ssq = 0.0f;
            #pragma unroll
            for (int j = 0; j < 4; ++j) {
                const float pre = rs1[i] * (acc2[i][j] - mu1[i] * sn[j]) + zw[j];
                u[j] = gelu_f(pre);
                ssum += u[j]; ssq += u[j] * u[j];
            }
            #pragma unroll
            for (int o = 1; o < 16; o <<= 1) {
                ssum += __shfl_xor(ssum, o, 64);
                ssq  += __shfl_xor(ssq,  o, 64);
            }
            const float m2 = ssum * (1.0f / 64.0f);
            const float rs2 = rsqrtf(ssq * (1.0f / 64.0f) - m2 * m2 + 1e-5f);
            float p[4] = {0.0f, 0.0f, 0.0f, 0.0f};
            #pragma unroll
            for (int j = 0; j < 4; ++j)
                #pragma unroll
                for (int c = 0; c < 4; ++c) p[c] += u[j] * w3[j][c];
            #pragma unroll
            for (int c = 0; c < 4; ++c)
                #pragma unroll
                for (int o = 1; o < 16; o <<= 1) p[c] += __shfl_xor(p[c], o, 64);
            float r = p[0];
            if (tc == 1) r = p[1];
            else if (tc == 2) r = p[2];
            else if (tc == 3) r = p[3];
            if (tc < 4)
                out_node[(size_t)(node0 + node) * 4 + tc] =
                    rs2 * (r - m2 * sn3) + cn3;
        }
    }
}

// ---------------------------------------------------------------------------
// Kernel C: fused edge path. 15625 blocks x 256 threads, 64 edges/block.
// f16 LDS tile (17.9 KB -> 8 blocks/CU); all arithmetic fp32.
// ---------------------------------------------------------------------------
__global__ __launch_bounds__(256, 4) void edge_kernel(
    const int* __restrict__ src, const int* __restrict__ dst,
    const int* __restrict__ n2g,
    const float* __restrict__ ws,
    float* __restrict__ out_edge)
{
    __shared__ _Float16 tile[64][136];
    __shared__ int gsrc[64];
    __shared__ int gdst[64];
    const int t = threadIdx.x;
    const int e0 = blockIdx.x * 64;

    if (t < 64) {
        gsrc[t] = n2g[src[e0 + t]];
        gdst[t] = n2g[dst[e0 + t]];
    }
    __syncthreads();

    // stage y = f16(gelu(P1b[gs] + P2[gd]))  (raw, no LN)
    {
        const int r0 = t >> 5;
        const int c4 = (t & 31) * 4;
        #pragma unroll
        for (int m = 0; m < 8; ++m) {
            const int rr = r0 + m * 8;
            const float4 a = *(const float4*)(ws + WS_P1B + (size_t)gsrc[rr] * 128 + c4);
            const float4 b = *(const float4*)(ws + WS_P2  + (size_t)gdst[rr] * 128 + c4);
            h4 hv;
            hv[0] = (_Float16)gelu_f(a.x + b.x);
            hv[1] = (_Float16)gelu_f(a.y + b.y);
            hv[2] = (_Float16)gelu_f(a.z + b.z);
            hv[3] = (_Float16)gelu_f(a.w + b.w);
            *(h4*)&tile[rr][c4] = hv;
        }
    }
    __syncthreads();

    const int tr = t >> 4;
    const int tc = t & 15;

    // per-row mu/rstd over the (f16-rounded) y — consistent with GEMM inputs
    float mu1[4], rs1[4];
    #pragma unroll
    for (int i = 0; i < 4; ++i) {
        const int r = tr + 16 * i;
        h8 hv = *(const h8*)&tile[r][tc * 8];
        float x[8];
        #pragma unroll
        for (int j = 0; j < 8; ++j) x[j] = (float)hv[j];
        float ssum = 0.0f, ssq = 0.0f;
        #pragma unroll
        for (int j = 0; j < 8; ++j) { ssum += x[j]; ssq += x[j] * x[j]; }
        #pragma unroll
        for (int o = 1; o < 16; o <<= 1) {
            ssum += __shfl_xor(ssum, o, 64);
            ssq  += __shfl_xor(ssq,  o, 64);
        }
        const float m = ssum * (1.0f / 128.0f);
        mu1[i] = m;
        rs1[i] = rsqrtf(ssq * (1.0f / 128.0f) - m * m + 1e-5f);
    }

    // ---- layer 2 (LN folded): pre = rs*(y@WG2E - mu*SE) + C1E ----
    float acc2[4][4];
    #pragma unroll
    for (int i = 0; i < 4; ++i)
        #pragma unroll
        for (int j = 0; j < 4; ++j) acc2[i][j] = 0.0f;

    const float* wg2 = ws + WS_WG2E;
    for (int k4 = 0; k4 < 128; k4 += 4) {
        float w2[4][4];
        #pragma unroll
        for (int kk = 0; kk < 4; ++kk) {
            float4 wv = *(const float4*)(wg2 + (size_t)(k4 + kk) * 64 + tc * 4);
            w2[kk][0] = wv.x; w2[kk][1] = wv.y; w2[kk][2] = wv.z; w2[kk][3] = wv.w;
        }
        #pragma unroll
        for (int i = 0; i < 4; ++i) {
            h4 hv = *(const h4*)&tile[tr + 16 * i][k4];
            float in4[4] = {(float)hv[0], (float)hv[1], (float)hv[2], (float)hv[3]};
            #pragma unroll
            for (int kk = 0; kk < 4; ++kk)
                #pragma unroll
                for (int j = 0; j < 4; ++j)
                    acc2[i][j] += in4[kk] * w2[kk][j];
        }
    }

    // epilogue: u = gelu(pre); out = rs2*(u@W3GE - mu2*S3E) + C3E
    {
        float4 sev = *(const float4*)(ws + WS_SE + tc * 4);
        float se[4] = {sev.x, sev.y, sev.z, sev.w};
        float4 c1v = *(const float4*)(ws + WS_C1E + tc * 4);
        float c1[4] = {c1v.x, c1v.y, c1v.z, c1v.w};
        float w3[4][3];
        #pragma unroll
        for (int j = 0; j < 4; ++j) {
            const float* wp = ws + WS_W3GE + (size_t)(tc * 4 + j) * 3;
            w3[j][0] = wp[0]; w3[j][1] = wp[1]; w3[j][2] = wp[2];
        }
        const int cidx = (tc < 3) ? tc : 0;
        const float s3 = ws[WS_S3E + cidx];
        const float c3 = ws[WS_C3E + cidx];
        #pragma unroll
        for (int i = 0; i < 4; ++i) {
            const int e = e0 + tr + 16 * i;
            float u[4];
            float ssum = 0.0f, ssq = 0.0f;
            #pragma unroll
            for (int j = 0; j < 4; ++j) {
                const float pre = rs1[i] * (acc2[i][j] - mu1[i] * se[j]) + c1[j];
                u[j] = gelu_f(pre);
                ssum += u[j]; ssq += u[j] * u[j];
            }
            #pragma unroll
            for (int o = 1; o < 16; o <<= 1) {
                ssum += __shfl_xor(ssum, o, 64);
                ssq  += __shfl_xor(ssq,  o, 64);
            }
            const float m2 = ssum * (1.0f / 64.0f);
            const float rs2 = rsqrtf(ssq * (1.0f / 64.0f) - m2 * m2 + 1e-5f);
            float p[3] = {0.0f, 0.0f, 0.0f};
            #pragma unroll
            for (int j = 0; j < 4; ++j)
                #pragma unroll
                for (int c = 0; c < 3; ++c) p[c] += u[j] * w3[j][c];
            #pragma unroll
            for (int c = 0; c < 3; ++c)
                #pragma unroll
                for (int o = 1; o < 16; o <<= 1) p[c] += __shfl_xor(p[c], o, 64);
            float r = p[0];
            if (tc == 1) r = p[1];
            else if (tc == 2) r = p[2];
            if (tc < 3)
                out_edge[(size_t)e * 3 + tc] = rs2 * (r - m2 * s3) + c3;
        }
    }
}

extern "C" void kernel_launch(void* const* d_in, const int* in_sizes, int n_in,
                              void* d_out, int out_size, void* d_ws, size_t ws_size,
                              hipStream_t stream) {
    const float* z        = (const float*)d_in[0];
    const float* node_emb = (const float*)d_in[1];
    const int*   n2g      = (const int*)d_in[2];
    const int*   src      = (const int*)d_in[3];
    const int*   dst      = (const int*)d_in[4];
    const float* lp_w  = (const float*)d_in[5];
    const float* lp_b  = (const float*)d_in[6];
    const float* lp_g  = (const float*)d_in[7];
    const float* lp_be = (const float*)d_in[8];
    const float* ne_w  = (const float*)d_in[9];
    const float* ne_b  = (const float*)d_in[10];
    const float* ne_g  = (const float*)d_in[11];
    const float* ne_be = (const float*)d_in[12];
    const float* nd_w1 = (const float*)d_in[13];
    const float* nd_b1 = (const float*)d_in[14];
    const float* nd_g  = (const float*)d_in[15];
    const float* nd_be = (const float*)d_in[16];
    const float* nd_w2 = (const float*)d_in[17];
    const float* nd_b2 = (const float*)d_in[18];
    const float* ed_w1 = (const float*)d_in[19];
    const float* ed_b1 = (const float*)d_in[20];
    const float* ed_g1 = (const float*)d_in[21];
    const float* ed_be1= (const float*)d_in[22];
    const float* ed_w2 = (const float*)d_in[23];
    const float* ed_b2 = (const float*)d_in[24];
    const float* ed_g2 = (const float*)d_in[25];
    const float* ed_be2= (const float*)d_in[26];
    const float* ed_w3 = (const float*)d_in[27];
    const float* ed_b3 = (const float*)d_in[28];
    const float* en_w1 = (const float*)d_in[29];
    const float* en_b1 = (const float*)d_in[30];
    const float* en_g  = (const float*)d_in[31];
    const float* en_be = (const float*)d_in[32];
    const float* en_w2 = (const float*)d_in[33];
    const float* en_b2 = (const float*)d_in[34];
    const float* st_w1 = (const float*)d_in[35];
    const float* st_b1 = (const float*)d_in[36];
    const float* st_g  = (const float*)d_in[37];
    const float* st_be = (const float*)d_in[38];
    const float* st_w2 = (const float*)d_in[39];
    const float* st_b2 = (const float*)d_in[40];

    float* out       = (float*)d_out;
    float* out_node  = out;                                   // N*4
    float* out_edge  = out + (size_t)NN * 4;                  // E*3
    float* out_pe    = out + (size_t)NN * 4 + (size_t)NE * 3; // B*2
    float* out_ps    = out_pe + (size_t)NB * 2;               // B*9

    float* ws = (float*)d_ws;

    prep_kernel<<<1, 256, 0, stream>>>(
        ed_g1, ed_be1, ed_w2, ed_b2, ed_g2, ed_be2, ed_w3, ed_b3,
        ne_g, ne_be, nd_w1, nd_b1, nd_g, nd_be, nd_w2, nd_b2, ws);

    graph_kernel<<<NB, 128, 0, stream>>>(
        z, lp_w, lp_b, lp_g, lp_be, ed_w1, ed_b1, nd_w1,
        en_w1, en_b1, en_g, en_be, en_w2, en_b2,
        st_w1, st_b1, st_g, st_be, st_w2, st_b2,
        ws, out_pe, out_ps);

    node_kernel<<<NN / 64, 256, 0, stream>>>(
        node_emb, n2g, ne_w, ne_b, ws, out_node);

    edge_kernel<<<NE / 64, 256, 0, stream>>>(
        src, dst, n2g, ws, out_edge);
}